// Round 1
// baseline (122.919 us; speedup 1.0000x reference)
//
#include <hip/hip_runtime.h>

typedef __attribute__((ext_vector_type(8))) short short8;
typedef __attribute__((ext_vector_type(4))) float f32x4;

#define LNP_YSTRIDE 1032   // 16 rows x (1024+8) bf16

__device__ __forceinline__ unsigned short f2bf(float f) {
  union { float f; unsigned u; } v; v.f = f;
  unsigned r = v.u + 0x7FFFu + ((v.u >> 16) & 1u);  // RNE
  return (unsigned short)(r >> 16);
}
__device__ __forceinline__ unsigned pack2(float a, float b) {
  return (unsigned)f2bf(a) | ((unsigned)f2bf(b) << 16);
}
__device__ __forceinline__ short8 packW(float4 a, float4 b) {
  union { short8 s; unsigned u[4]; } r;
  r.u[0] = pack2(a.x, a.y); r.u[1] = pack2(a.z, a.w);
  r.u[2] = pack2(b.x, b.y); r.u[3] = pack2(b.z, b.w);
  return r.s;
}

// 8-row target LN + projection (unchanged, verified): wave w LNs rows w*2..w*2+1;
// MFMA K=1024 split 4 ways (wave w: k-steps w*8..w*8+7), both h-tiles per wave.
// A rows 8..15 are uninitialized LDS — D rows are independent; only rows 0..7 stored.
__device__ __forceinline__ void lnproj8_t(
    const float* __restrict__ X, const float* __restrict__ g, const float* __restrict__ bia,
    const float* __restrict__ W, const float* __restrict__ pb, const float* __restrict__ msk,
    unsigned short* __restrict__ outb, int row0, unsigned short* Yl, float* pd, int tid)
{
  const int w = tid >> 6, lid = tid & 63, l = tid & 15, q = (tid >> 4) & 3;
  const f32x4 zero = {0.f, 0.f, 0.f, 0.f};

  #pragma unroll
  for (int rr = 0; rr < 2; ++rr) {
    const int row = w * 2 + rr;
    const float* xr = X + (size_t)(row0 + row) * 1024;
    float4 v[4];
    float s = 0.f, s2 = 0.f;
    #pragma unroll
    for (int k = 0; k < 4; ++k) {
      v[k] = *(const float4*)(xr + 4 * lid + 256 * k);
      s  += (v[k].x + v[k].y) + (v[k].z + v[k].w);
      s2 += (v[k].x * v[k].x + v[k].y * v[k].y) + (v[k].z * v[k].z + v[k].w * v[k].w);
    }
    #pragma unroll
    for (int off = 32; off >= 1; off >>= 1) { s += __shfl_xor(s, off, 64); s2 += __shfl_xor(s2, off, 64); }
    const float mu = s * (1.f / 1024.f);
    const float rs = rsqrtf(s2 * (1.f / 1024.f) - mu * mu + 1e-5f);
    #pragma unroll
    for (int k = 0; k < 4; ++k) {
      float4 gg = *(const float4*)(g + 4 * lid + 256 * k);
      float4 bb = *(const float4*)(bia + 4 * lid + 256 * k);
      unsigned* yd = (unsigned*)(Yl + row * LNP_YSTRIDE + 4 * lid + 256 * k);
      yd[0] = pack2((v[k].x - mu) * rs * gg.x + bb.x, (v[k].y - mu) * rs * gg.y + bb.y);
      yd[1] = pack2((v[k].z - mu) * rs * gg.z + bb.z, (v[k].w - mu) * rs * gg.w + bb.w);
    }
  }
  __syncthreads();

  f32x4 acc0 = zero, acc1 = zero;
  #pragma unroll
  for (int ss = 0; ss < 8; ++ss) {
    const int s = w * 8 + ss;
    short8 af = *(const short8*)(Yl + l * LNP_YSTRIDE + s * 32 + q * 8);   // A[m][k]
    const float* wp0 = W + (size_t)l * 1024 + s * 32 + q * 8;              // h = l
    const float* wp1 = W + (size_t)(16 + l) * 1024 + s * 32 + q * 8;       // h = 16+l
    acc0 = __builtin_amdgcn_mfma_f32_16x16x32_bf16(af, packW(*(const float4*)wp0, *(const float4*)(wp0 + 4)), acc0, 0, 0, 0);
    acc1 = __builtin_amdgcn_mfma_f32_16x16x32_bf16(af, packW(*(const float4*)wp1, *(const float4*)(wp1 + 4)), acc1, 0, 0, 0);
  }
  if (w > 0 && q < 2) {
    #pragma unroll
    for (int r = 0; r < 4; ++r) {
      const int rl = q * 4 + r;                        // D row 0..7
      pd[(w - 1) * 256 + rl * 16 + l]       = acc0[r];
      pd[(w - 1) * 256 + 128 + rl * 16 + l] = acc1[r];
    }
  }
  __syncthreads();
  if (w == 0 && q < 2) {
    #pragma unroll
    for (int ht = 0; ht < 2; ++ht) {
      const int h = ht * 16 + l;
      const float pbv = pb[h];
      #pragma unroll
      for (int r = 0; r < 4; ++r) {
        const int rl = q * 4 + r, rg = row0 + rl;
        float val = (ht ? acc1[r] : acc0[r]) + pbv;
        #pragma unroll
        for (int k = 0; k < 3; ++k) val += pd[k * 256 + ht * 128 + rl * 16 + l];
        outb[(size_t)rg * 32 + h] = f2bf(val * msk[rg]);
      }
    }
  }
}

// 16-row LN+proj (unchanged) — drug side (ROWLEN=128).
template<int ROWLEN>
__device__ __forceinline__ void lnproj(
    const float* __restrict__ X, const float* __restrict__ g, const float* __restrict__ bia,
    const float* __restrict__ W, const float* __restrict__ pb, const float* __restrict__ msk,
    unsigned short* __restrict__ outb, int row0, unsigned short* Yl, float* pd, int tid)
{
  const int w = tid >> 6, lid = tid & 63, l = tid & 15, q = (tid >> 4) & 3;

  #pragma unroll
  for (int rr = 0; rr < 4; ++rr) {
    const int row = w * 4 + rr;
    const float* xr = X + (size_t)(row0 + row) * ROWLEN;
    float2 v = *(const float2*)(xr + 2 * lid);
    float s = v.x + v.y, s2 = v.x * v.x + v.y * v.y;
    #pragma unroll
    for (int off = 32; off >= 1; off >>= 1) { s += __shfl_xor(s, off, 64); s2 += __shfl_xor(s2, off, 64); }
    const float mu = s * (1.f / ROWLEN);
    const float rs = rsqrtf(s2 * (1.f / ROWLEN) - mu * mu + 1e-5f);
    float2 gg = *(const float2*)(g + 2 * lid);
    float2 bb = *(const float2*)(bia + 2 * lid);
    *(unsigned*)(Yl + row * LNP_YSTRIDE + 2 * lid) =
        pack2((v.x - mu) * rs * gg.x + bb.x, (v.y - mu) * rs * gg.y + bb.y);
  }
  __syncthreads();

  const int KST = ROWLEN / 32;
  const int ht = w & 1, kh = w >> 1;
  const int h = ht * 16 + l;
  f32x4 acc = {0.f, 0.f, 0.f, 0.f};
  #pragma unroll
  for (int s = kh * (KST / 2); s < kh * (KST / 2) + KST / 2; ++s) {
    short8 af = *(const short8*)(Yl + l * LNP_YSTRIDE + s * 32 + q * 8);
    const float* wp = W + (size_t)h * ROWLEN + s * 32 + q * 8;
    short8 bf = packW(*(const float4*)wp, *(const float4*)(wp + 4));
    acc = __builtin_amdgcn_mfma_f32_16x16x32_bf16(af, bf, acc, 0, 0, 0);
  }
  if (w >= 2) {
    #pragma unroll
    for (int r = 0; r < 4; ++r) pd[ht * 256 + (q * 4 + r) * 16 + l] = acc[r];
  }
  __syncthreads();
  if (w < 2) {
    const float pbv = pb[h];
    #pragma unroll
    for (int r = 0; r < 4; ++r) {
      const int rg = row0 + q * 4 + r;
      float val = acc[r] + pd[ht * 256 + (q * 4 + r) * 16 + l] + pbv;
      val *= msk[rg];
      outb[(size_t)rg * 32 + h] = f2bf(val);
    }
  }
}

// k_pre grid (400 blocks): [0,256) target LN+proj (8 rows);
// [256,272) drug LN+proj (16 rows); [272,400) mask out.
// (W_out transpose stage REMOVED — H-factorization reads W_out contiguously.)
__global__ __launch_bounds__(256) void k_pre(
    const float* __restrict__ tgt, const float* __restrict__ drg,
    const float* __restrict__ tmask, const float* __restrict__ dmask,
    const float* __restrict__ ln_t_g, const float* __restrict__ ln_t_b,
    const float* __restrict__ ln_d_g, const float* __restrict__ ln_d_b,
    const float* __restrict__ W_t, const float* __restrict__ b_t,
    const float* __restrict__ W_d, const float* __restrict__ b_d,
    unsigned short* __restrict__ tfb, unsigned short* __restrict__ dfb,
    float* __restrict__ mask_out)
{
  __shared__ unsigned short Yl[16 * LNP_YSTRIDE];
  __shared__ float pd[3 * 256];
  const int blk = blockIdx.x, tid = threadIdx.x;
  if (blk < 256) {
    lnproj8_t(tgt, ln_t_g, ln_t_b, W_t, b_t, tmask, tfb, blk * 8, Yl, pd, tid);
  } else if (blk < 272) {
    lnproj<128>(drg, ln_d_g, ln_d_b, W_d, b_d, dmask, dfb, (blk - 256) * 16, Yl, pd, tid);
  } else {
    const int base = ((blk - 272) * 256 + tid) * 4;   // flat index into [4,512,64]
    const int b = base >> 15;
    const float tm = tmask[base >> 6];
    float4 d = *(const float4*)(dmask + b * 64 + (base & 63));
    float4 o; o.x = tm * d.x; o.y = tm * d.y; o.z = tm * d.z; o.w = tm * d.w;
    *(float4*)(mask_out + base) = o;
  }
}

// k_mid: H[b][m][ic] = sum_e W_out[ic*32+e] * df[b][m][e]   (ic = i*32+c, K=32)
// 256 blocks = b(4) x icg(64); wave w handles m-tile w, 4 ic-tiles each.
// A = W_out rows (CONTIGUOUS reads, f32->bf16 pack), B = df fragments from dfb.
__global__ __launch_bounds__(256) void k_mid(
    const float* __restrict__ W_out, const unsigned short* __restrict__ dfb,
    unsigned short* __restrict__ Hb)
{
  const int id = blockIdx.x;
  const int b = id >> 6, icg = id & 63;
  const int tid = threadIdx.x, w = tid >> 6, l = tid & 15, q = (tid >> 4) & 3;
  const f32x4 zero = {0.f, 0.f, 0.f, 0.f};
  const int m = w * 16 + l;
  short8 bf = *(const short8*)(dfb + (size_t)(b * 64 + m) * 32 + q * 8);
  #pragma unroll
  for (int u = 0; u < 4; ++u) {
    const int ic0 = icg * 64 + u * 16;
    const float* ap = W_out + (size_t)(ic0 + l) * 32 + q * 8;      // A[row=ic][k=e]
    short8 af = packW(*(const float4*)ap, *(const float4*)(ap + 4));
    f32x4 d = __builtin_amdgcn_mfma_f32_16x16x32_bf16(af, bf, zero, 0, 0, 0);
    // D: col = m = l, rows = ic0 + q*4 + r  -> 4 consecutive ic per lane
    uint2 hv; hv.x = pack2(d[0], d[1]); hv.y = pack2(d[2], d[3]);
    *(uint2*)(Hb + (size_t)(b * 64 + m) * 4096 + ic0 + q * 4) = hv;
  }
}

// k_main: out[b,n,m,i] = (sum_c H[b,m,i*32+c] * tf[b,n,c] + b_out[i]) * tm[n]*dm[m]
// Pure streaming GEMM, K=32, no LDS, no barriers. 2048 blocks = b(4) x m(64) x ng(8).
// Block tile: one m, 128 i, 64 n. Wave w: i in [w*32, w*32+32). One MFMA per 16x16
// output tile; D rows = i (consecutive per lane) -> coalesced float4 stores over i.
__global__ __launch_bounds__(256) void k_main(
    const unsigned short* __restrict__ Hb, const unsigned short* __restrict__ tfb,
    const float* __restrict__ b_out, const float* __restrict__ tmask,
    const float* __restrict__ dmask, float* __restrict__ out)
{
  const int id = blockIdx.x;
  const int b = id >> 9, m = (id >> 3) & 63, ng = id & 7;
  const int tid = threadIdx.x, w = tid >> 6, l = tid & 15, q = (tid >> 4) & 3;
  const int n0 = ng * 64;
  const f32x4 zero = {0.f, 0.f, 0.f, 0.f};

  // A-frags: H[b][m][i][c], lane l -> row i = itile0 + l, k-chunk q*8
  const unsigned short* hrow = Hb + (size_t)(b * 64 + m) * 4096;
  short8 a0 = *(const short8*)(hrow + (w * 32 + l) * 32 + q * 8);
  short8 a1 = *(const short8*)(hrow + (w * 32 + 16 + l) * 32 + q * 8);

  // B-frags: tf[b][n0 + t2*16 + l][c], lane l -> col n
  short8 bfr[4];
  #pragma unroll
  for (int t2 = 0; t2 < 4; ++t2)
    bfr[t2] = *(const short8*)(tfb + (size_t)(b * 512 + n0 + t2 * 16 + l) * 32 + q * 8);

  const float4 bo0 = *(const float4*)(b_out + w * 32 + q * 4);
  const float4 bo1 = *(const float4*)(b_out + w * 32 + 16 + q * 4);
  const float dmv = dmask[b * 64 + m];
  float tmv[4];
  #pragma unroll
  for (int t2 = 0; t2 < 4; ++t2)
    tmv[t2] = tmask[b * 512 + n0 + t2 * 16 + l] * dmv;

  #pragma unroll
  for (int t2 = 0; t2 < 4; ++t2) {
    const size_t rbase = ((size_t)(b * 512 + n0 + t2 * 16 + l) * 64 + m) * 128;
    const float s = tmv[t2];
    f32x4 d0 = __builtin_amdgcn_mfma_f32_16x16x32_bf16(a0, bfr[t2], zero, 0, 0, 0);
    f32x4 d1 = __builtin_amdgcn_mfma_f32_16x16x32_bf16(a1, bfr[t2], zero, 0, 0, 0);
    f32x4 o0, o1;
    o0[0] = (d0[0] + bo0.x) * s; o0[1] = (d0[1] + bo0.y) * s;
    o0[2] = (d0[2] + bo0.z) * s; o0[3] = (d0[3] + bo0.w) * s;
    o1[0] = (d1[0] + bo1.x) * s; o1[1] = (d1[1] + bo1.y) * s;
    o1[2] = (d1[2] + bo1.z) * s; o1[3] = (d1[3] + bo1.w) * s;
    __builtin_nontemporal_store(o0, (f32x4*)(out + rbase + w * 32 + q * 4));
    __builtin_nontemporal_store(o1, (f32x4*)(out + rbase + w * 32 + 16 + q * 4));
  }
}

extern "C" void kernel_launch(void* const* d_in, const int* in_sizes, int n_in,
                              void* d_out, int out_size, void* d_ws, size_t ws_size,
                              hipStream_t stream)
{
  const float* tgt    = (const float*)d_in[0];
  const float* drg    = (const float*)d_in[1];
  const float* tmask  = (const float*)d_in[2];
  const float* dmask  = (const float*)d_in[3];
  const float* ln_t_g = (const float*)d_in[4];
  const float* ln_t_b = (const float*)d_in[5];
  const float* ln_d_g = (const float*)d_in[6];
  const float* ln_d_b = (const float*)d_in[7];
  const float* W_t    = (const float*)d_in[8];
  const float* b_t    = (const float*)d_in[9];
  const float* W_d    = (const float*)d_in[10];
  const float* b_d    = (const float*)d_in[11];
  const float* W_out  = (const float*)d_in[12];
  const float* b_out  = (const float*)d_in[13];

  float* out = (float*)d_out;
  float* mask_out = out + (size_t)4 * 512 * 64 * 128;   // second output

  char* ws = (char*)d_ws;
  unsigned short* Hb  = (unsigned short*)(ws);                     // 4*64*4096 bf16 = 2 MB
  unsigned short* tfb = (unsigned short*)(ws + 2097152);           // 2048*32 bf16 = 128 KB
  unsigned short* dfb = (unsigned short*)(ws + 2097152 + 131072);  // 256*32 bf16 = 16 KB

  k_pre<<<dim3(400), dim3(256), 0, stream>>>(
      tgt, drg, tmask, dmask, ln_t_g, ln_t_b, ln_d_g, ln_d_b,
      W_t, b_t, W_d, b_d, tfb, dfb, mask_out);
  k_mid<<<dim3(256), dim3(256), 0, stream>>>(W_out, dfb, Hb);
  k_main<<<dim3(2048), dim3(256), 0, stream>>>(Hb, tfb, b_out, tmask, dmask, out);
}

// Round 2
// 119.069 us; speedup vs baseline: 1.0323x; 1.0323x over previous
//
#include <hip/hip_runtime.h>

typedef __attribute__((ext_vector_type(8))) short short8;
typedef __attribute__((ext_vector_type(4))) float f32x4;

#define LNP_YSTRIDE 1032   // 16 rows x (1024+8) bf16 (target path)
#define DYSTR 136          // drug-H path: 64 rows x (128+8) bf16

__device__ __forceinline__ unsigned short f2bf(float f) {
  union { float f; unsigned u; } v; v.f = f;
  unsigned r = v.u + 0x7FFFu + ((v.u >> 16) & 1u);  // RNE
  return (unsigned short)(r >> 16);
}
__device__ __forceinline__ unsigned pack2(float a, float b) {
  return (unsigned)f2bf(a) | ((unsigned)f2bf(b) << 16);
}
__device__ __forceinline__ short8 packW(float4 a, float4 b) {
  union { short8 s; unsigned u[4]; } r;
  r.u[0] = pack2(a.x, a.y); r.u[1] = pack2(a.z, a.w);
  r.u[2] = pack2(b.x, b.y); r.u[3] = pack2(b.z, b.w);
  return r.s;
}

// 8-row target LN + projection (unchanged, verified).
__device__ __forceinline__ void lnproj8_t(
    const float* __restrict__ X, const float* __restrict__ g, const float* __restrict__ bia,
    const float* __restrict__ W, const float* __restrict__ pb, const float* __restrict__ msk,
    unsigned short* __restrict__ outb, int row0, unsigned short* Yl, float* pd, int tid)
{
  const int w = tid >> 6, lid = tid & 63, l = tid & 15, q = (tid >> 4) & 3;
  const f32x4 zero = {0.f, 0.f, 0.f, 0.f};

  #pragma unroll
  for (int rr = 0; rr < 2; ++rr) {
    const int row = w * 2 + rr;
    const float* xr = X + (size_t)(row0 + row) * 1024;
    float4 v[4];
    float s = 0.f, s2 = 0.f;
    #pragma unroll
    for (int k = 0; k < 4; ++k) {
      v[k] = *(const float4*)(xr + 4 * lid + 256 * k);
      s  += (v[k].x + v[k].y) + (v[k].z + v[k].w);
      s2 += (v[k].x * v[k].x + v[k].y * v[k].y) + (v[k].z * v[k].z + v[k].w * v[k].w);
    }
    #pragma unroll
    for (int off = 32; off >= 1; off >>= 1) { s += __shfl_xor(s, off, 64); s2 += __shfl_xor(s2, off, 64); }
    const float mu = s * (1.f / 1024.f);
    const float rs = rsqrtf(s2 * (1.f / 1024.f) - mu * mu + 1e-5f);
    #pragma unroll
    for (int k = 0; k < 4; ++k) {
      float4 gg = *(const float4*)(g + 4 * lid + 256 * k);
      float4 bb = *(const float4*)(bia + 4 * lid + 256 * k);
      unsigned* yd = (unsigned*)(Yl + row * LNP_YSTRIDE + 4 * lid + 256 * k);
      yd[0] = pack2((v[k].x - mu) * rs * gg.x + bb.x, (v[k].y - mu) * rs * gg.y + bb.y);
      yd[1] = pack2((v[k].z - mu) * rs * gg.z + bb.z, (v[k].w - mu) * rs * gg.w + bb.w);
    }
  }
  __syncthreads();

  f32x4 acc0 = zero, acc1 = zero;
  #pragma unroll
  for (int ss = 0; ss < 8; ++ss) {
    const int s = w * 8 + ss;
    short8 af = *(const short8*)(Yl + l * LNP_YSTRIDE + s * 32 + q * 8);   // A[m][k]
    const float* wp0 = W + (size_t)l * 1024 + s * 32 + q * 8;              // h = l
    const float* wp1 = W + (size_t)(16 + l) * 1024 + s * 32 + q * 8;       // h = 16+l
    acc0 = __builtin_amdgcn_mfma_f32_16x16x32_bf16(af, packW(*(const float4*)wp0, *(const float4*)(wp0 + 4)), acc0, 0, 0, 0);
    acc1 = __builtin_amdgcn_mfma_f32_16x16x32_bf16(af, packW(*(const float4*)wp1, *(const float4*)(wp1 + 4)), acc1, 0, 0, 0);
  }
  if (w > 0 && q < 2) {
    #pragma unroll
    for (int r = 0; r < 4; ++r) {
      const int rl = q * 4 + r;                        // D row 0..7
      pd[(w - 1) * 256 + rl * 16 + l]       = acc0[r];
      pd[(w - 1) * 256 + 128 + rl * 16 + l] = acc1[r];
    }
  }
  __syncthreads();
  if (w == 0 && q < 2) {
    #pragma unroll
    for (int ht = 0; ht < 2; ++ht) {
      const int h = ht * 16 + l;
      const float pbv = pb[h];
      #pragma unroll
      for (int r = 0; r < 4; ++r) {
        const int rl = q * 4 + r, rg = row0 + rl;
        float val = (ht ? acc1[r] : acc0[r]) + pbv;
        #pragma unroll
        for (int k = 0; k < 3; ++k) val += pd[k * 256 + ht * 128 + rl * 16 + l];
        outb[(size_t)rg * 32 + h] = f2bf(val * msk[rg]);
      }
    }
  }
}

// H-block: recompute drug LN+proj for batch b (waves independent, NO barriers),
// then H[b][m][ic] = sum_e W_out[ic*32+e] * df[b][m][e] for this block's 64 ic.
// Step B computes df with A=W_d (rows h) so D col = m = lane -> an 8-shfl in-wave
// transpose assembles the df B-fragment; no LDS round trip for df.
__device__ __forceinline__ void drug_h(
    const float* __restrict__ drg, const float* __restrict__ g, const float* __restrict__ bia,
    const float* __restrict__ W_d, const float* __restrict__ b_d, const float* __restrict__ dmask,
    const float* __restrict__ W_out, unsigned short* __restrict__ Hb,
    int b, int icg, unsigned short* Yl, int tid)
{
  const int w = tid >> 6, lid = tid & 63, l = tid & 15, q = (tid >> 4) & 3;
  const f32x4 zero = {0.f, 0.f, 0.f, 0.f};

  // Step A: LN rows w*16 .. w*16+15 of drg[b] -> Yl (bf16, stride DYSTR)
  #pragma unroll
  for (int rr = 0; rr < 16; ++rr) {
    const int row = w * 16 + rr;
    const float* xr = drg + (size_t)(b * 64 + row) * 128;
    float2 v = *(const float2*)(xr + 2 * lid);
    float s = v.x + v.y, s2 = v.x * v.x + v.y * v.y;
    #pragma unroll
    for (int off = 32; off >= 1; off >>= 1) { s += __shfl_xor(s, off, 64); s2 += __shfl_xor(s2, off, 64); }
    const float mu = s * (1.f / 128.f);
    const float rs = rsqrtf(s2 * (1.f / 128.f) - mu * mu + 1e-5f);
    float2 gg = *(const float2*)(g + 2 * lid);
    float2 bb = *(const float2*)(bia + 2 * lid);
    *(unsigned*)(Yl + row * DYSTR + 2 * lid) =
        pack2((v.x - mu) * rs * gg.x + bb.x, (v.y - mu) * rs * gg.y + bb.y);
  }

  // Step B: df = Y @ W_d^T + b_d, masked.  A = W_d rows (h), B = Y rows (m=w*16+l).
  // D: row = h = q*4+r (+16 for acc1), col = m-local = l.
  f32x4 acc0 = zero, acc1 = zero;
  #pragma unroll
  for (int s = 0; s < 4; ++s) {
    short8 bf = *(const short8*)(Yl + (w * 16 + l) * DYSTR + s * 32 + q * 8);
    const float* wp0 = W_d + (size_t)l * 128 + s * 32 + q * 8;
    const float* wp1 = W_d + (size_t)(16 + l) * 128 + s * 32 + q * 8;
    acc0 = __builtin_amdgcn_mfma_f32_16x16x32_bf16(packW(*(const float4*)wp0, *(const float4*)(wp0 + 4)), bf, acc0, 0, 0, 0);
    acc1 = __builtin_amdgcn_mfma_f32_16x16x32_bf16(packW(*(const float4*)wp1, *(const float4*)(wp1 + 4)), bf, acc1, 0, 0, 0);
  }
  const float dmv = dmask[b * 64 + w * 16 + l];     // col m = l
  const float4 bd0 = *(const float4*)(b_d + q * 4);
  const float4 bd1 = *(const float4*)(b_d + 16 + q * 4);
  unsigned u0a = pack2((acc0[0] + bd0.x) * dmv, (acc0[1] + bd0.y) * dmv);
  unsigned u0b = pack2((acc0[2] + bd0.z) * dmv, (acc0[3] + bd0.w) * dmv);
  unsigned u1a = pack2((acc1[0] + bd1.x) * dmv, (acc1[1] + bd1.y) * dmv);
  unsigned u1b = pack2((acc1[2] + bd1.z) * dmv, (acc1[3] + bd1.w) * dmv);

  // In-wave transpose: thread (q,l) needs df[m=w*16+l][e = q*8 .. q*8+7].
  // e-quads q*8..+3 and q*8+4..+7 live in lanes srcA/srcB = ((q&1)*2 {+1})*16 + l,
  // in acc0 (e<16, q<2) or acc1 (e>=16, q>=2).
  const int srcA = ((q & 1) << 5) + l;
  const int srcB = srcA + 16;
  unsigned a0 = __shfl((int)u0a, srcA, 64), a1 = __shfl((int)u1a, srcA, 64);
  unsigned b0 = __shfl((int)u0b, srcA, 64), b1 = __shfl((int)u1b, srcA, 64);
  unsigned c0 = __shfl((int)u0a, srcB, 64), c1 = __shfl((int)u1a, srcB, 64);
  unsigned d0 = __shfl((int)u0b, srcB, 64), d1 = __shfl((int)u1b, srcB, 64);
  const bool hi = (q >= 2);
  union { short8 s; unsigned u[4]; } bfrag;
  bfrag.u[0] = hi ? a1 : a0;
  bfrag.u[1] = hi ? b1 : b0;
  bfrag.u[2] = hi ? c1 : c0;
  bfrag.u[3] = hi ? d1 : d0;

  // Step C: H slice. A = W_out rows (ic, CONTIGUOUS), B = df frag.
  const int m = w * 16 + l;
  #pragma unroll
  for (int u = 0; u < 4; ++u) {
    const int ic0 = icg * 64 + u * 16;
    const float* ap = W_out + (size_t)(ic0 + l) * 32 + q * 8;
    short8 af = packW(*(const float4*)ap, *(const float4*)(ap + 4));
    f32x4 d = __builtin_amdgcn_mfma_f32_16x16x32_bf16(af, bfrag.s, zero, 0, 0, 0);
    uint2 hv; hv.x = pack2(d[0], d[1]); hv.y = pack2(d[2], d[3]);
    *(uint2*)(Hb + (size_t)(b * 64 + m) * 4096 + ic0 + q * 4) = hv;
  }
}

// k_pre grid (640 blocks): [0,256) target LN+proj (8 rows);
// [256,512) drug LN+proj+H (b = (blk-256)>>6, icg = (blk-256)&63); [512,640) mask.
__global__ __launch_bounds__(256) void k_pre(
    const float* __restrict__ tgt, const float* __restrict__ drg,
    const float* __restrict__ tmask, const float* __restrict__ dmask,
    const float* __restrict__ ln_t_g, const float* __restrict__ ln_t_b,
    const float* __restrict__ ln_d_g, const float* __restrict__ ln_d_b,
    const float* __restrict__ W_t, const float* __restrict__ b_t,
    const float* __restrict__ W_d, const float* __restrict__ b_d,
    const float* __restrict__ W_out,
    unsigned short* __restrict__ tfb, unsigned short* __restrict__ Hb,
    float* __restrict__ mask_out)
{
  __shared__ unsigned short Yl[16 * LNP_YSTRIDE];
  __shared__ float pd[3 * 256];
  const int blk = blockIdx.x, tid = threadIdx.x;
  if (blk < 256) {
    lnproj8_t(tgt, ln_t_g, ln_t_b, W_t, b_t, tmask, tfb, blk * 8, Yl, pd, tid);
  } else if (blk < 512) {
    drug_h(drg, ln_d_g, ln_d_b, W_d, b_d, dmask, W_out, Hb,
           (blk - 256) >> 6, (blk - 256) & 63, Yl, tid);
  } else {
    const int base = ((blk - 512) * 256 + tid) * 4;   // flat index into [4,512,64]
    const int b = base >> 15;
    const float tm = tmask[base >> 6];
    float4 d = *(const float4*)(dmask + b * 64 + (base & 63));
    float4 o; o.x = tm * d.x; o.y = tm * d.y; o.z = tm * d.z; o.w = tm * d.w;
    *(float4*)(mask_out + base) = o;
  }
}

// k_main: out[b,n,m,i] = (sum_c H[b,m,i*32+c] * tf[b,n,c] + b_out[i]) * tm[n]*dm[m]
// Pure streaming GEMM, K=32, no LDS, no barriers. 2048 blocks = b(4) x m(64) x ng(8).
__global__ __launch_bounds__(256) void k_main(
    const unsigned short* __restrict__ Hb, const unsigned short* __restrict__ tfb,
    const float* __restrict__ b_out, const float* __restrict__ tmask,
    const float* __restrict__ dmask, float* __restrict__ out)
{
  const int id = blockIdx.x;
  const int b = id >> 9, m = (id >> 3) & 63, ng = id & 7;
  const int tid = threadIdx.x, w = tid >> 6, l = tid & 15, q = (tid >> 4) & 3;
  const int n0 = ng * 64;
  const f32x4 zero = {0.f, 0.f, 0.f, 0.f};

  const unsigned short* hrow = Hb + (size_t)(b * 64 + m) * 4096;
  short8 a0 = *(const short8*)(hrow + (w * 32 + l) * 32 + q * 8);
  short8 a1 = *(const short8*)(hrow + (w * 32 + 16 + l) * 32 + q * 8);

  short8 bfr[4];
  #pragma unroll
  for (int t2 = 0; t2 < 4; ++t2)
    bfr[t2] = *(const short8*)(tfb + (size_t)(b * 512 + n0 + t2 * 16 + l) * 32 + q * 8);

  const float4 bo0 = *(const float4*)(b_out + w * 32 + q * 4);
  const float4 bo1 = *(const float4*)(b_out + w * 32 + 16 + q * 4);
  const float dmv = dmask[b * 64 + m];
  float tmv[4];
  #pragma unroll
  for (int t2 = 0; t2 < 4; ++t2)
    tmv[t2] = tmask[b * 512 + n0 + t2 * 16 + l] * dmv;

  #pragma unroll
  for (int t2 = 0; t2 < 4; ++t2) {
    const size_t rbase = ((size_t)(b * 512 + n0 + t2 * 16 + l) * 64 + m) * 128;
    const float s = tmv[t2];
    f32x4 d0 = __builtin_amdgcn_mfma_f32_16x16x32_bf16(a0, bfr[t2], zero, 0, 0, 0);
    f32x4 d1 = __builtin_amdgcn_mfma_f32_16x16x32_bf16(a1, bfr[t2], zero, 0, 0, 0);
    f32x4 o0, o1;
    o0[0] = (d0[0] + bo0.x) * s; o0[1] = (d0[1] + bo0.y) * s;
    o0[2] = (d0[2] + bo0.z) * s; o0[3] = (d0[3] + bo0.w) * s;
    o1[0] = (d1[0] + bo1.x) * s; o1[1] = (d1[1] + bo1.y) * s;
    o1[2] = (d1[2] + bo1.z) * s; o1[3] = (d1[3] + bo1.w) * s;
    *(f32x4*)(out + rbase + w * 32 + q * 4) = o0;
    *(f32x4*)(out + rbase + w * 32 + 16 + q * 4) = o1;
  }
}

extern "C" void kernel_launch(void* const* d_in, const int* in_sizes, int n_in,
                              void* d_out, int out_size, void* d_ws, size_t ws_size,
                              hipStream_t stream)
{
  const float* tgt    = (const float*)d_in[0];
  const float* drg    = (const float*)d_in[1];
  const float* tmask  = (const float*)d_in[2];
  const float* dmask  = (const float*)d_in[3];
  const float* ln_t_g = (const float*)d_in[4];
  const float* ln_t_b = (const float*)d_in[5];
  const float* ln_d_g = (const float*)d_in[6];
  const float* ln_d_b = (const float*)d_in[7];
  const float* W_t    = (const float*)d_in[8];
  const float* b_t    = (const float*)d_in[9];
  const float* W_d    = (const float*)d_in[10];
  const float* b_d    = (const float*)d_in[11];
  const float* W_out  = (const float*)d_in[12];
  const float* b_out  = (const float*)d_in[13];

  float* out = (float*)d_out;
  float* mask_out = out + (size_t)4 * 512 * 64 * 128;   // second output

  char* ws = (char*)d_ws;
  unsigned short* Hb  = (unsigned short*)(ws);            // 4*64*4096 bf16 = 2 MB
  unsigned short* tfb = (unsigned short*)(ws + 2097152);  // 2048*32 bf16 = 128 KB

  k_pre<<<dim3(640), dim3(256), 0, stream>>>(
      tgt, drg, tmask, dmask, ln_t_g, ln_t_b, ln_d_g, ln_d_b,
      W_t, b_t, W_d, b_d, W_out, tfb, Hb, mask_out);
  k_main<<<dim3(2048), dim3(256), 0, stream>>>(Hb, tfb, b_out, tmask, dmask, out);
}